// Round 6
// baseline (140.935 us; speedup 1.0000x reference)
//
#include <hip/hip_runtime.h>
#include <math.h>

#define L_SEQ 1024
#define HE 512          // H*E
#define NBATCH 32
#define TOPK 6
#define NZ 8            // K-split: 4 batches = K-chunk of 2048 per z
#define NT 64           // K-steps of 32 fp32

using bf16x8 = __attribute__((ext_vector_type(8))) short;
using f32x4  = __attribute__((ext_vector_type(4))) float;
using f32x2v = __attribute__((ext_vector_type(2))) float;
using bfx2v  = __attribute__((ext_vector_type(2))) __bf16;

// pack two fp32 -> two bf16 (RNE) in one uint; lowers to v_cvt_pk_bf16_f32
__device__ __forceinline__ unsigned int bf2(float lo, float hi) {
  f32x2v f; f[0] = lo; f[1] = hi;
  bfx2v h = __builtin_convertvector(f, bfx2v);
  return *(unsigned int*)&h;
}

__device__ __forceinline__ bf16x8 pack8(float4 a, float4 b) {
  unsigned int u[4] = {bf2(a.x, a.y), bf2(a.z, a.w), bf2(b.x, b.y), bf2(b.z, b.w)};
  return *(bf16x8*)u;
}

// async global->LDS, 16B per lane, linear dest (wave-uniform base + lane*16)
__device__ __forceinline__ void gload_lds16(const float* g, char* l) {
  __builtin_amdgcn_global_load_lds(
      (const __attribute__((address_space(1))) void*)g,
      (__attribute__((address_space(3))) void*)l, 16, 0, 0);
}

// ---------------------------------------------------------------------------
// Kernel 1: fused partial-Gram (bf16 MFMA, fp32 staged via global_load_lds)
// + per-block diagonal reduction. Block (x,y,z): 128x128 tile over K-chunk
// 2048 (batches 4z..4z+3), diag-reduced into partial[blin][tau].
// fp32 tiles staged ASYNC to LDS (no VGPR round-trip, loads in flight across
// the whole compute phase); fp32->bf16 conversion at ds_read time.
// Swizzle: LDS dest linear; per-lane global SOURCE pre-swizzled (chunk
// h ^= row&7, 16B granules); ds_read applies the same XOR (rule #21).
// 4 waves (2x2), per-wave 64x64, BK=32, double-buffered 2x32KB.
// ---------------------------------------------------------------------------
__global__ __launch_bounds__(256, 2) void gram_fused_kernel(
    const float* __restrict__ q, const float* __restrict__ k,
    float* __restrict__ partial)
{
  __shared__ char smem[65536];  // buf0: A@0,B@16K; buf1: A@32K,B@48K; tail reuses

  const int tid = threadIdx.x;      // 0..255
  const int l   = tid & 63;
  const int wid = tid >> 6;         // 0..3
  const int wrm = (wid >> 1) * 64;  // wave row offset (0/64)
  const int wcn = (wid & 1) * 64;   // wave col offset (0/64)
  const int s0  = blockIdx.x * 128;
  const int t0  = blockIdx.y * 128;
  const int z   = blockIdx.z;

  // staging precompute: inst i stages rows [(wid*4+i)*8, +8), lane t -> 16B
  // chunk (row = base+ (lane>>3), h = lane&7); source chunk = h ^ (row&7).
  unsigned int aoff[4], boff[4];    // per-lane global float offsets (row part)
  int ldsoff[4];                    // wave-uniform LDS byte offset
  #pragma unroll
  for (int i = 0; i < 4; ++i) {
    const int row = (wid * 4 + i) * 8 + (l >> 3);
    const int hsrc = (l & 7) ^ (row & 7);
    ldsoff[i] = (wid * 4 + i) * 1024;
    aoff[i] = (unsigned int)(s0 + row) * HE + (hsrc << 2);
    boff[i] = (unsigned int)(t0 + row) * HE + (hsrc << 2);
  }

  f32x4 acc[4][4] = {};
  const int l15 = l & 15;
  const int blk = l >> 4;

  // per-lane ds_read byte offsets (within an A/B region), frag m/n:
  // row = w*+f*16+l15; two 16B chunks (2blk)^(row&7), (2blk+1)^(row&7)
  int ra0[4], ra1[4], rb0[4], rb1[4];
  #pragma unroll
  for (int f = 0; f < 4; ++f) {
    const int rowa = wrm + f * 16 + l15;
    ra0[f] = rowa * 128 + ((((blk << 1) | 0) ^ (rowa & 7)) << 4);
    ra1[f] = rowa * 128 + ((((blk << 1) | 1) ^ (rowa & 7)) << 4);
    const int rowb = wcn + f * 16 + l15;
    rb0[f] = rowb * 128 + ((((blk << 1) | 0) ^ (rowb & 7)) << 4);
    rb1[f] = rowb * 128 + ((((blk << 1) | 1) ^ (rowb & 7)) << 4);
  }

  // K-step t: batch = 4z + (t>>4), col window = (t&15)*32 floats
  #define KSTEP_BASE(t) \
    ((unsigned int)(4 * z + ((t) >> 4)) * (L_SEQ * HE) + (((t) & 15) << 5))
  #define STAGE(t, p) do {                                         \
    const unsigned int ub = KSTEP_BASE(t);                         \
    char* Ab_ = smem + ((p) << 15);                                \
    char* Bb_ = Ab_ + 16384;                                       \
    _Pragma("unroll")                                              \
    for (int i_ = 0; i_ < 4; ++i_) {                               \
      gload_lds16(q + ub + aoff[i_], Ab_ + ldsoff[i_]);            \
      gload_lds16(k + ub + boff[i_], Bb_ + ldsoff[i_]);            \
    }                                                              \
  } while (0)

  STAGE(0, 0);
  __syncthreads();   // vmcnt(0) drain + barrier: buf0 staged

  for (int t = 0; t < NT; ++t) {
    if (t + 1 < NT) STAGE(t + 1, (t + 1) & 1);   // async, in flight all phase

    const char* Ab = smem + ((t & 1) << 15);
    const char* Bb = Ab + 16384;

    bf16x8 af[4], bfr[4];
    #pragma unroll
    for (int f = 0; f < 4; ++f) {
      const float4 a0 = *(const float4*)(Ab + ra0[f]);
      const float4 a1 = *(const float4*)(Ab + ra1[f]);
      af[f] = pack8(a0, a1);
      const float4 b0 = *(const float4*)(Bb + rb0[f]);
      const float4 b1 = *(const float4*)(Bb + rb1[f]);
      bfr[f] = pack8(b0, b1);
    }

    __builtin_amdgcn_s_setprio(1);
    #pragma unroll
    for (int m = 0; m < 4; ++m)
      #pragma unroll
      for (int n = 0; n < 4; ++n)
        acc[m][n] = __builtin_amdgcn_mfma_f32_16x16x32_bf16(
            af[m], bfr[n], acc[m][n], 0, 0, 0);
    __builtin_amdgcn_s_setprio(0);

    __syncthreads();   // drains this step's stage loads (issued pre-compute)
  }

  // ---- fused diagonal reduction (reuse smem) ----
  // Gs: 32 x 128 fp32 chunk, stride 132. bins: 1024 fp32 at byte 16896.
  float* Gs   = (float*)smem;
  float* bins = (float*)(smem + 16896);

  for (int i = tid; i < 1024; i += 256) bins[i] = 0.f;

  #pragma unroll
  for (int cc = 0; cc < 4; ++cc) {   // tile rows [cc*32, cc*32+32)
    __syncthreads();                 // bins/prev-phase visible

    // spill: waves whose wrm covers this chunk
    // C/D layout: col = lane&15, row = (lane>>4)*4 + reg  [m89/m91]
    if ((wid >> 1) == (cc >> 1)) {
      #pragma unroll
      for (int mp = 0; mp < 2; ++mp) {
        const int m = (cc & 1) * 2 + mp;
        #pragma unroll
        for (int j = 0; j < 4; ++j) {
          const int ds = mp * 16 + blk * 4 + j;   // 0..31
          #pragma unroll
          for (int n = 0; n < 4; ++n)
            Gs[ds * 132 + wcn + n * 16 + l15] = acc[m][n][j];
        }
      }
    }
    __syncthreads();                 // Gs visible

    if (tid < 159) {
      const int o = tid - 127;       // diag offset ds-dt in [-127, 31]
      float s = 0.f;
      #pragma unroll
      for (int i = 0; i < 32; ++i) { // fixed-trip, predicated
        const int dt = i - o;
        const bool ok = (dt >= 0) && (dt < 128);
        const int dtc = ok ? dt : 0;
        const float v = Gs[i * 132 + dtc];
        s += ok ? v : 0.f;
      }
      const int tau = (s0 - t0 + 32 * cc + o + 4096) & (L_SEQ - 1);
      bins[tau] += s;                // unique tau per thread per phase
    }
  }
  __syncthreads();

  const int blin = blockIdx.x + 8 * blockIdx.y + 64 * blockIdx.z;  // 0..511
  for (int i = tid; i < 1024; i += 256)
    partial[(size_t)blin * 1024 + i] = bins[i];
}

// ---------------------------------------------------------------------------
// Kernel 2: c[tau] = (1/16384) * sum_{blk<512} partial[blk][tau]
// ---------------------------------------------------------------------------
__global__ __launch_bounds__(256) void reduce_kernel(
    const float* __restrict__ partial, float* __restrict__ c)
{
  const int tid = threadIdx.x;
  const int g16 = tid & 15;
  const int brow = tid >> 4;
  const int tau = blockIdx.x * 16 + g16;
  float s = 0.f;
  for (int it = 0; it < 32; ++it)
    s += partial[(size_t)(brow + (it << 4)) * 1024 + tau];
  __shared__ float sm[16][17];
  sm[brow][g16] = s;
  __syncthreads();
  if (tid < 16) {
    float t = 0.f;
    #pragma unroll
    for (int r = 0; r < 16; ++r) t += sm[r][tid];
    c[blockIdx.x * 16 + tid] = t * (1.0f / 16384.0f);
  }
}

// ---------------------------------------------------------------------------
// Kernel 3: top-6 (desc, smaller-index tie-break) + softmax. 1 block.
// ---------------------------------------------------------------------------
__global__ __launch_bounds__(256) void topk_kernel(
    const float* __restrict__ c, int* __restrict__ idx_out,
    float* __restrict__ w_out)
{
  __shared__ float vals[L_SEQ];
  __shared__ float rv[256];
  __shared__ int ri[256];
  __shared__ float topv[TOPK];
  __shared__ int topi[TOPK];
  const int tid = threadIdx.x;
  for (int i = tid; i < L_SEQ; i += 256) vals[i] = c[i];
  __syncthreads();

  for (int kk = 0; kk < TOPK; ++kk) {
    float bv = -INFINITY;
    int bi = 1 << 30;
    for (int i = tid; i < L_SEQ; i += 256) {
      const float v = vals[i];
      if (v > bv || (v == bv && i < bi)) { bv = v; bi = i; }
    }
    rv[tid] = bv; ri[tid] = bi;
    __syncthreads();
    for (int off = 128; off > 0; off >>= 1) {
      if (tid < off) {
        const float v2 = rv[tid + off];
        const int i2 = ri[tid + off];
        if (v2 > rv[tid] || (v2 == rv[tid] && i2 < ri[tid])) {
          rv[tid] = v2; ri[tid] = i2;
        }
      }
      __syncthreads();
    }
    if (tid == 0) {
      topv[kk] = rv[0];
      topi[kk] = ri[0];
      vals[ri[0]] = -INFINITY;
    }
    __syncthreads();
  }

  if (tid == 0) {
    const float m = topv[0];
    float e[TOPK], sum = 0.f;
    for (int i = 0; i < TOPK; ++i) { e[i] = expf(topv[i] - m); sum += e[i]; }
    const float inv = 1.0f / sum;
    for (int i = 0; i < TOPK; ++i) { w_out[i] = e[i] * inv; idx_out[i] = topi[i]; }
  }
}

// ---------------------------------------------------------------------------
// Kernel 4: out[b,l,h,e] = sum_k w[k] * v[b,(l+idx[k])%L,h,e]
// ---------------------------------------------------------------------------
__global__ __launch_bounds__(256) void agg_kernel(
    const float* __restrict__ v, const int* __restrict__ idx,
    const float* __restrict__ w, float4* __restrict__ out)
{
  __shared__ int sidx[TOPK];
  __shared__ float sw[TOPK];
  if (threadIdx.x < TOPK) {
    sidx[threadIdx.x] = idx[threadIdx.x];
    sw[threadIdx.x] = w[threadIdx.x];
  }
  __syncthreads();

  const int i = blockIdx.x * 256 + threadIdx.x;   // 0 .. 2^22-1
  const int he4 = i & 127;                        // 512/4
  const int l = (i >> 7) & (L_SEQ - 1);
  const int b = i >> 17;
  const float4* vb = (const float4*)v + (size_t)b * (L_SEQ * 128);

  float4 acc = make_float4(0.f, 0.f, 0.f, 0.f);
  #pragma unroll
  for (int kk = 0; kk < TOPK; ++kk) {
    const int src = (l + sidx[kk]) & (L_SEQ - 1);
    const float4 vv = vb[(size_t)src * 128 + he4];
    const float wk = sw[kk];
    acc.x += wk * vv.x; acc.y += wk * vv.y;
    acc.z += wk * vv.z; acc.w += wk * vv.w;
  }
  out[i] = acc;
}

// ---------------------------------------------------------------------------
extern "C" void kernel_launch(void* const* d_in, const int* in_sizes, int n_in,
                              void* d_out, int out_size, void* d_ws, size_t ws_size,
                              hipStream_t stream) {
  const float* q = (const float*)d_in[0];
  const float* k = (const float*)d_in[1];
  const float* v = (const float*)d_in[2];
  // d_in[3] = attn_mask (scalar 0) -- unused

  float* out = (float*)d_out;
  // partial diag bins: 512 blocks x 1024 taus x 4B = 2 MB at the front of
  // d_out; fully consumed by reduce_kernel before agg overwrites d_out.
  float* partial = out;

  float* c = (float*)d_ws;                              // 1024 floats
  int* idxp = (int*)((char*)d_ws + 4096);               // 6 ints
  float* wp = (float*)((char*)d_ws + 4096 + 64);        // 6 floats

  dim3 gGram(L_SEQ / 128, L_SEQ / 128, NZ);
  gram_fused_kernel<<<gGram, 256, 0, stream>>>(q, k, partial);
  reduce_kernel<<<64, 256, 0, stream>>>(partial, c);
  topk_kernel<<<1, 256, 0, stream>>>(c, idxp, wp);
  agg_kernel<<<(L_SEQ * NBATCH * 128) / 256, 256, 0, stream>>>(v, idxp, wp,
                                                               (float4*)out);
}

// Round 7
// 110.672 us; speedup vs baseline: 1.2734x; 1.2734x over previous
//
#include <hip/hip_runtime.h>
#include <math.h>

#define L_SEQ 1024
#define HE 512          // H*E
#define NBATCH 32
#define TOPK 6
#define NZ 16           // K-split: 2 batches = K-chunk of 1024 per z
#define NT 16           // K-steps of 64

using bf16x8 = __attribute__((ext_vector_type(8))) short;
using f32x4  = __attribute__((ext_vector_type(4))) float;
using f32x2v = __attribute__((ext_vector_type(2))) float;
using bfx2v  = __attribute__((ext_vector_type(2))) __bf16;

// pack two fp32 -> two bf16 (RNE) in one uint; lowers to v_cvt_pk_bf16_f32
__device__ __forceinline__ unsigned int bf2(float lo, float hi) {
  f32x2v f; f[0] = lo; f[1] = hi;
  bfx2v h = __builtin_convertvector(f, bfx2v);
  return *(unsigned int*)&h;
}

// ---------------------------------------------------------------------------
// Kernel 1: fused partial-Gram (bf16 MFMA) + per-block diagonal reduction.
// Round-5 geometry (proven 86.5us): 256x256 tile, 8 waves (2Mx4N), per-wave
// 128x64, BK=64, double-buffered swizzled LDS (2x64KB).
// NEW: issue-early/wait-late pipeline enforced with sched_barrier(0) fences
// (loads ISSUED before the MFMA phase; first USE -- the bf16 pack -- after
// it), last iteration peeled so the loop body is branch-free; bijective
// XCD-aware block swizzle (each XCD works 2 z-chunks, L2-resident).
// ---------------------------------------------------------------------------
__global__ __launch_bounds__(512, 2) void gram_fused_kernel(
    const float* __restrict__ q, const float* __restrict__ k,
    float* __restrict__ partial)
{
  __shared__ char smem[131072];  // 2 x (As 32KB + Bs 32KB); tail reuses it

  // bijective XCD swizzle: 256 blocks, 8 XCDs, 32 consecutive per XCD
  const int bid = blockIdx.x + 4 * blockIdx.y + 16 * blockIdx.z;
  const int swz = (bid & 7) * 32 + (bid >> 3);
  const int bx = swz & 3, by = (swz >> 2) & 3, bz = swz >> 4;

  const int tid = threadIdx.x;       // 0..511
  const int l   = tid & 63;
  const int wid = tid >> 6;          // 0..7
  const int wrm = (wid >> 2) * 128;  // wave row offset (0 / 128)
  const int wcn = (wid & 3) * 64;    // wave col offset (0/64/128/192)
  const int s0  = bx * 256;
  const int t0  = by * 256;
  const int z   = bz;                // batch pair index

  // staging chunks: it in 0..3, id = it*512+tid -> (row 0..255, c8 0..7)
  int swoff[4];
  unsigned int agoff[4], bgoff[4];   // 32-bit global float offsets
  #pragma unroll
  for (int it = 0; it < 4; ++it) {
    const int id  = (it << 9) | tid;
    const int row = id >> 3;
    const int c8  = id & 7;
    swoff[it] = ((row << 7) + (c8 << 4)) ^ ((row & 7) << 4);
    agoff[it] = (unsigned int)(s0 + row) * HE + c8 * 8;
    bgoff[it] = (unsigned int)(t0 + row) * HE + c8 * 8;
  }

  f32x4 acc[8][4] = {};
  const int l15 = l & 15;
  const int blk = l >> 4;

  float4 ra0[4], ra1[4], rb0[4], rb1[4];

  #define LOADSTEP(t) do {                                                  \
    const unsigned int boff =                                               \
        (unsigned int)(z * 2 + ((t) >> 3)) * (L_SEQ * HE) + ((t) & 7) * 64; \
    _Pragma("unroll")                                                       \
    for (int it_ = 0; it_ < 4; ++it_) {                                     \
      ra0[it_] = *(const float4*)(q + boff + agoff[it_]);                   \
      ra1[it_] = *(const float4*)(q + boff + agoff[it_] + 4);               \
      rb0[it_] = *(const float4*)(k + boff + bgoff[it_]);                   \
      rb1[it_] = *(const float4*)(k + boff + bgoff[it_] + 4);               \
    }                                                                       \
  } while (0)

  #define PACKWRITE(p) do {                                                 \
    char* wbase_ = smem + ((p) << 16);                                      \
    _Pragma("unroll")                                                       \
    for (int it_ = 0; it_ < 4; ++it_) {                                     \
      uint4 pa_, pb_;                                                       \
      pa_.x = bf2(ra0[it_].x, ra0[it_].y); pa_.y = bf2(ra0[it_].z, ra0[it_].w); \
      pa_.z = bf2(ra1[it_].x, ra1[it_].y); pa_.w = bf2(ra1[it_].z, ra1[it_].w); \
      pb_.x = bf2(rb0[it_].x, rb0[it_].y); pb_.y = bf2(rb0[it_].z, rb0[it_].w); \
      pb_.z = bf2(rb1[it_].x, rb1[it_].y); pb_.w = bf2(rb1[it_].z, rb1[it_].w); \
      *(uint4*)(wbase_ + swoff[it_])         = pa_;                         \
      *(uint4*)(wbase_ + 32768 + swoff[it_]) = pb_;                         \
    }                                                                       \
  } while (0)

  #define MFMAPHASE(t) do {                                                 \
    const char* rbase = smem + (((t) & 1) << 16);                           \
    __builtin_amdgcn_s_setprio(1);                                          \
    _Pragma("unroll")                                                       \
    for (int kk = 0; kk < 2; ++kk) {                                        \
      bf16x8 bfr[4];                                                        \
      _Pragma("unroll")                                                     \
      for (int n = 0; n < 4; ++n) {                                         \
        const int rowb = wcn + n * 16 + l15;                                \
        const int offb =                                                    \
            ((rowb << 7) + (kk << 6) + (blk << 4)) ^ ((rowb & 7) << 4);     \
        bfr[n] = *(const bf16x8*)(rbase + 32768 + offb);                    \
      }                                                                     \
      _Pragma("unroll")                                                     \
      for (int mh = 0; mh < 2; ++mh) {                                      \
        bf16x8 af[4];                                                       \
        _Pragma("unroll")                                                   \
        for (int j = 0; j < 4; ++j) {                                       \
          const int rowa = wrm + (mh * 4 + j) * 16 + l15;                   \
          const int offa =                                                  \
              ((rowa << 7) + (kk << 6) + (blk << 4)) ^ ((rowa & 7) << 4);   \
          af[j] = *(const bf16x8*)(rbase + offa);                           \
        }                                                                   \
        _Pragma("unroll")                                                   \
        for (int j = 0; j < 4; ++j)                                         \
          _Pragma("unroll")                                                 \
          for (int n = 0; n < 4; ++n)                                       \
            acc[mh * 4 + j][n] = __builtin_amdgcn_mfma_f32_16x16x32_bf16(   \
                af[j], bfr[n], acc[mh * 4 + j][n], 0, 0, 0);                \
      }                                                                     \
    }                                                                       \
    __builtin_amdgcn_s_setprio(0);                                          \
  } while (0)

  // prologue: tile 0 -> buf0
  LOADSTEP(0);
  PACKWRITE(0);
  __syncthreads();

  // steady state: issue loads(t+1) | MFMA(buf t) | pack+write(buf t+1) | bar
  for (int t = 0; t < NT - 1; ++t) {
    LOADSTEP(t + 1);
    __builtin_amdgcn_sched_barrier(0);   // loads must ISSUE before MFMA phase
    MFMAPHASE(t);
    __builtin_amdgcn_sched_barrier(0);   // first USE (pack) stays after MFMA
    PACKWRITE((t + 1) & 1);
    __syncthreads();
  }
  // peeled last step
  MFMAPHASE(NT - 1);

  // ---- fused diagonal reduction (reuse smem) ----
  // Gs: 64 x 256 fp32 chunk, stride 264 (2-way max on spill).
  // bins: 1024 fp32 at byte 67584.
  float* Gs   = (float*)smem;
  float* bins = (float*)(smem + 67584);

  __syncthreads();   // all MFMA LDS reads done before overwrite
  for (int i = tid; i < 1024; i += 512) bins[i] = 0.f;

  #pragma unroll
  for (int cc = 0; cc < 4; ++cc) {   // row-chunk [64cc, 64cc+64)
    __syncthreads();                 // bins zeroed / previous phase done

    // spill: waves whose wrm covers this chunk
    // C/D layout: col = lane&15, row = (lane>>4)*4 + reg  [m89/m91]
    if ((wid >> 2) == (cc >> 1)) {
      #pragma unroll
      for (int mp = 0; mp < 4; ++mp) {
        const int m = (cc & 1) * 4 + mp;
        #pragma unroll
        for (int j = 0; j < 4; ++j) {
          const int ds = mp * 16 + blk * 4 + j;
          #pragma unroll
          for (int n = 0; n < 4; ++n)
            Gs[ds * 264 + wcn + n * 16 + l15] = acc[m][n][j];
        }
      }
    }
    __syncthreads();                 // Gs visible

    if (tid < 319) {
      const int o = tid - 255;       // diag offset ds-dt in [-255, 63]
      float s = 0.f;
      #pragma unroll
      for (int i = 0; i < 64; ++i) { // fixed-trip, predicated -> pipelined
        const int dt = i - o;
        const bool ok = (dt >= 0) && (dt < 256);
        const int dtc = ok ? dt : 0;
        const float v = Gs[i * 264 + dtc];
        s += ok ? v : 0.f;
      }
      const int tau = (s0 - t0 + 64 * cc + o + 4096) & (L_SEQ - 1);
      bins[tau] += s;                // unique tau per thread per phase
    }
  }
  __syncthreads();

  const int blin = bx + 4 * by + 16 * bz;   // 0..255 (bijective)
  for (int i = tid; i < 1024; i += 512)
    partial[(size_t)blin * 1024 + i] = bins[i];
}

// ---------------------------------------------------------------------------
// Kernel 2: c[tau] = (1/16384) * sum_{blk<256} partial[blk][tau]
// ---------------------------------------------------------------------------
__global__ __launch_bounds__(256) void reduce_kernel(
    const float* __restrict__ partial, float* __restrict__ c)
{
  const int tid = threadIdx.x;
  const int g16 = tid & 15;
  const int brow = tid >> 4;
  const int tau = blockIdx.x * 16 + g16;
  float s = 0.f;
  for (int it = 0; it < 16; ++it)
    s += partial[(size_t)(brow + (it << 4)) * 1024 + tau];
  __shared__ float sm[16][17];
  sm[brow][g16] = s;
  __syncthreads();
  if (tid < 16) {
    float t = 0.f;
    #pragma unroll
    for (int r = 0; r < 16; ++r) t += sm[r][tid];
    c[blockIdx.x * 16 + tid] = t * (1.0f / 16384.0f);
  }
}

// ---------------------------------------------------------------------------
// Kernel 3: top-6 (desc, smaller-index tie-break) + softmax. 1 block.
// ---------------------------------------------------------------------------
__global__ __launch_bounds__(256) void topk_kernel(
    const float* __restrict__ c, int* __restrict__ idx_out,
    float* __restrict__ w_out)
{
  __shared__ float vals[L_SEQ];
  __shared__ float rv[256];
  __shared__ int ri[256];
  __shared__ float topv[TOPK];
  __shared__ int topi[TOPK];
  const int tid = threadIdx.x;
  for (int i = tid; i < L_SEQ; i += 256) vals[i] = c[i];
  __syncthreads();

  for (int kk = 0; kk < TOPK; ++kk) {
    float bv = -INFINITY;
    int bi = 1 << 30;
    for (int i = tid; i < L_SEQ; i += 256) {
      const float v = vals[i];
      if (v > bv || (v == bv && i < bi)) { bv = v; bi = i; }
    }
    rv[tid] = bv; ri[tid] = bi;
    __syncthreads();
    for (int off = 128; off > 0; off >>= 1) {
      if (tid < off) {
        const float v2 = rv[tid + off];
        const int i2 = ri[tid + off];
        if (v2 > rv[tid] || (v2 == rv[tid] && i2 < ri[tid])) {
          rv[tid] = v2; ri[tid] = i2;
        }
      }
      __syncthreads();
    }
    if (tid == 0) {
      topv[kk] = rv[0];
      topi[kk] = ri[0];
      vals[ri[0]] = -INFINITY;
    }
    __syncthreads();
  }

  if (tid == 0) {
    const float m = topv[0];
    float e[TOPK], sum = 0.f;
    for (int i = 0; i < TOPK; ++i) { e[i] = expf(topv[i] - m); sum += e[i]; }
    const float inv = 1.0f / sum;
    for (int i = 0; i < TOPK; ++i) { w_out[i] = e[i] * inv; idx_out[i] = topi[i]; }
  }
}

// ---------------------------------------------------------------------------
// Kernel 4: out[b,l,h,e] = sum_k w[k] * v[b,(l+idx[k])%L,h,e]
// ---------------------------------------------------------------------------
__global__ __launch_bounds__(256) void agg_kernel(
    const float* __restrict__ v, const int* __restrict__ idx,
    const float* __restrict__ w, float4* __restrict__ out)
{
  __shared__ int sidx[TOPK];
  __shared__ float sw[TOPK];
  if (threadIdx.x < TOPK) {
    sidx[threadIdx.x] = idx[threadIdx.x];
    sw[threadIdx.x] = w[threadIdx.x];
  }
  __syncthreads();

  const int i = blockIdx.x * 256 + threadIdx.x;   // 0 .. 2^22-1
  const int he4 = i & 127;                        // 512/4
  const int l = (i >> 7) & (L_SEQ - 1);
  const int b = i >> 17;
  const float4* vb = (const float4*)v + (size_t)b * (L_SEQ * 128);

  float4 acc = make_float4(0.f, 0.f, 0.f, 0.f);
  #pragma unroll
  for (int kk = 0; kk < TOPK; ++kk) {
    const int src = (l + sidx[kk]) & (L_SEQ - 1);
    const float4 vv = vb[(size_t)src * 128 + he4];
    const float wk = sw[kk];
    acc.x += wk * vv.x; acc.y += wk * vv.y;
    acc.z += wk * vv.z; acc.w += wk * vv.w;
  }
  out[i] = acc;
}

// ---------------------------------------------------------------------------
extern "C" void kernel_launch(void* const* d_in, const int* in_sizes, int n_in,
                              void* d_out, int out_size, void* d_ws, size_t ws_size,
                              hipStream_t stream) {
  const float* q = (const float*)d_in[0];
  const float* k = (const float*)d_in[1];
  const float* v = (const float*)d_in[2];
  // d_in[3] = attn_mask (scalar 0) -- unused

  float* out = (float*)d_out;
  // partial diag bins: 256 blocks x 1024 taus x 4B = 1 MB at the front of
  // d_out; fully consumed by reduce_kernel before agg overwrites d_out.
  float* partial = out;

  float* c = (float*)d_ws;                              // 1024 floats
  int* idxp = (int*)((char*)d_ws + 4096);               // 6 ints
  float* wp = (float*)((char*)d_ws + 4096 + 64);        // 6 floats

  dim3 gGram(L_SEQ / 256, L_SEQ / 256, NZ);
  gram_fused_kernel<<<gGram, 512, 0, stream>>>(q, k, partial);
  reduce_kernel<<<64, 256, 0, stream>>>(partial, c);
  topk_kernel<<<1, 256, 0, stream>>>(c, idxp, wp);
  agg_kernel<<<(L_SEQ * NBATCH * 128) / 256, 256, 0, stream>>>(v, idxp, wp,
                                                               (float4*)out);
}